// Round 8
// baseline (2498.796 us; speedup 1.0000x reference)
//
#include <hip/hip_runtime.h>

// ApsMultiheadAttention: E=1024 H=16 D=64 L=S=2048 N=2, fp32 throughout.
// Outputs: context (L,N,E) then att (N,L,S), concatenated in d_out.
//
// Round 7 resubmit (bench never ran: GPU acquisition timeout).
// Change under test vs round 6: K/V/Q staging via global_load_lds width=16
// (zero staging registers -> no spill against the VGPR=64 budget; round-6
// counters still showed ~380MB scratch RW, VGPR=64, VALU 30%).

#define EDIM   1024
#define HNUM   16
#define DDIM   64
#define LQ     2048
#define SK     2048
#define NBATCH 2

#define NEG_BIG (-3.0e38f)

// attn tiling
#define RB  8          // q-rows per block
#define ST  256        // s-tile staged in LDS
#define NT  (SK/ST)    // 8 tiles

__device__ __forceinline__ float wave_max_f(float v) {
#pragma unroll
  for (int o = 32; o > 0; o >>= 1) v = fmaxf(v, __shfl_xor(v, o));
  return v;
}
__device__ __forceinline__ float wave_sum_f(float v) {
#pragma unroll
  for (int o = 32; o > 0; o >>= 1) v += __shfl_xor(v, o);
  return v;
}

// async global->LDS, 16B per lane; LDS dest is wave-uniform base + lane*16.
__device__ __forceinline__ void gll16(const float* g, float* l) {
  __builtin_amdgcn_global_load_lds(
      (const __attribute__((address_space(1))) void*)g,
      (__attribute__((address_space(3))) void*)l,
      16, 0, 0);
}

// ---------------------------------------------------------------------------
// GEMM: C = A(MxK) @ W(NcxK)^T + bias.  Tile 128x128, BK=16, 256 threads,
// 8x8 micro-tile as 2x2 quadrants of 4x4. EPI: 0 plain row-major;
// 1 scatter (N,H,R,D); 2 scatter (N,H,D,R). Rows are (row,n), n fastest.
// (unchanged — validated)
template <int EPI>
__global__ __launch_bounds__(256) void gemm_k(
    const float* __restrict__ A, const float* __restrict__ W,
    const float* __restrict__ bias, float* __restrict__ C,
    const int M, const int K, const int Nc, const int R)
{
  __shared__ float As[16][132];
  __shared__ float Bs[16][132];
  const int t  = threadIdx.x;
  const int m0 = blockIdx.y * 128;
  const int n0 = blockIdx.x * 128;
  const int lr = t >> 2;
  const int lk = (t & 3) << 2;
  const int tx = t & 15;
  const int ty = t >> 4;

  float acc[2][2][4][4];
#pragma unroll
  for (int a = 0; a < 2; ++a)
#pragma unroll
    for (int b = 0; b < 2; ++b)
#pragma unroll
      for (int i = 0; i < 4; ++i)
#pragma unroll
        for (int j = 0; j < 4; ++j) acc[a][b][i][j] = 0.f;

  float4 ra0, ra1, rb0, rb1;
  ra0 = *(const float4*)&A[(size_t)(m0 + lr) * K + lk];
  ra1 = *(const float4*)&A[(size_t)(m0 + lr + 64) * K + lk];
  rb0 = *(const float4*)&W[(size_t)(n0 + lr) * K + lk];
  rb1 = *(const float4*)&W[(size_t)(n0 + lr + 64) * K + lk];

  for (int k0 = 0; k0 < K; k0 += 16) {
    __syncthreads();
    As[lk+0][lr]    = ra0.x; As[lk+1][lr]    = ra0.y; As[lk+2][lr]    = ra0.z; As[lk+3][lr]    = ra0.w;
    As[lk+0][lr+64] = ra1.x; As[lk+1][lr+64] = ra1.y; As[lk+2][lr+64] = ra1.z; As[lk+3][lr+64] = ra1.w;
    Bs[lk+0][lr]    = rb0.x; Bs[lk+1][lr]    = rb0.y; Bs[lk+2][lr]    = rb0.z; Bs[lk+3][lr]    = rb0.w;
    Bs[lk+0][lr+64] = rb1.x; Bs[lk+1][lr+64] = rb1.y; Bs[lk+2][lr+64] = rb1.z; Bs[lk+3][lr+64] = rb1.w;
    __syncthreads();
    const int kn = k0 + 16;
    if (kn < K) {
      ra0 = *(const float4*)&A[(size_t)(m0 + lr) * K + kn + lk];
      ra1 = *(const float4*)&A[(size_t)(m0 + lr + 64) * K + kn + lk];
      rb0 = *(const float4*)&W[(size_t)(n0 + lr) * K + kn + lk];
      rb1 = *(const float4*)&W[(size_t)(n0 + lr + 64) * K + kn + lk];
    }
#pragma unroll
    for (int kk = 0; kk < 16; ++kk) {
      const float4 a0 = *(const float4*)&As[kk][ty * 4];
      const float4 a1 = *(const float4*)&As[kk][ty * 4 + 64];
      const float4 b0 = *(const float4*)&Bs[kk][tx * 4];
      const float4 b1 = *(const float4*)&Bs[kk][tx * 4 + 64];
      const float av[2][4] = {{a0.x,a0.y,a0.z,a0.w},{a1.x,a1.y,a1.z,a1.w}};
      const float bv[2][4] = {{b0.x,b0.y,b0.z,b0.w},{b1.x,b1.y,b1.z,b1.w}};
#pragma unroll
      for (int qi = 0; qi < 2; ++qi)
#pragma unroll
        for (int i = 0; i < 4; ++i)
#pragma unroll
          for (int qj = 0; qj < 2; ++qj)
#pragma unroll
            for (int j = 0; j < 4; ++j)
              acc[qi][qj][i][j] = fmaf(av[qi][i], bv[qj][j], acc[qi][qj][i][j]);
    }
  }

#pragma unroll
  for (int qi = 0; qi < 2; ++qi)
#pragma unroll
    for (int i = 0; i < 4; ++i) {
      const int gr = m0 + qi * 64 + ty * 4 + i;
      const int row = gr / NBATCH;
      const int nb  = gr % NBATCH;
#pragma unroll
      for (int qj = 0; qj < 2; ++qj)
#pragma unroll
        for (int j = 0; j < 4; ++j) {
          const int gc = n0 + qj * 64 + tx * 4 + j;
          const float val = acc[qi][qj][i][j] + bias[gc];
          if constexpr (EPI == 0) {
            C[(size_t)gr * Nc + gc] = val;
          } else {
            const int h = gc >> 6, d = gc & 63;
            if constexpr (EPI == 1)
              C[(((size_t)nb * HNUM + h) * R + row) * DDIM + d] = val;
            else
              C[(((size_t)nb * HNUM + h) * DDIM + d) * (size_t)R + row] = val;
          }
        }
    }
}

// ---------------------------------------------------------------------------
// attn: grid = N*(L/RB) = 512 blocks, 1024 threads (16 waves).
// Dynamic LDS (138.2 KB): p[8][2048] | kv[16384] (K tiles then V tiles) |
// q[512] | part[4][8][64] | red[16][2] | m[8] | rinv[8].
// K tile in LDS: [d][s] (64 x 256); V tile: [s][d] (256 x 64); both staged
// with global_load_lds (zero staging registers).
//
// Thread maps:
//  A1/A2/att: rows {rr, rr+4} (rr=t>>8), col cc=t&255; slots s=j*256+cc.
//  B2 (PV):   rows {rr, rr+4}, d=t&63, s-quarter sq=(t>>6)&3.
__global__ __launch_bounds__(1024, 4) void attn_k(
    const float* __restrict__ qs, const float* __restrict__ kts,
    const float* __restrict__ vs, const float* __restrict__ amask,
    const unsigned char* __restrict__ kpm,
    float* __restrict__ ctx, float* __restrict__ att)
{
  extern __shared__ float lds[];
  float* p_lds = lds;                    // 16384 f
  float* kv    = lds + RB * SK;          // 16384 f
  float* q_lds = kv + 16384;             // 512 f
  float* part  = q_lds + 512;            // 2048 f
  float* red   = part + 2048;            // 32 f
  float* m_l   = red + 32;               // 8 f
  float* ri_l  = m_l + 8;                // 8 f

  const int t    = threadIdx.x;
  const int wg   = blockIdx.x;
  const int n    = wg >> 8;
  const int l0   = (wg & 255) * RB;
  const int wid  = t >> 6;
  const int lane = t & 63;
  const int rr   = t >> 8;        // 0..3 ; rows rr, rr+4
  const int cc   = t & 255;       // A1/A2 col within tile
  const int dd   = t & 63;        // B2 d
  const int sq   = (t >> 6) & 3;  // B2 s-quarter

  float attA[NT], attB[NT];
#pragma unroll
  for (int j = 0; j < NT; ++j) { attA[j] = 0.f; attB[j] = 0.f; }

  for (int h = 0; h < HNUM; ++h) {
    const int nh = n * HNUM + h;
    const float* ktb = kts + (size_t)nh * DDIM * SK;
    const float* vb  = vs  + (size_t)nh * SK * DDIM;

    // wave 'wid' stages K rows / V chunks wid*4 .. wid*4+3 (1KB each)
    auto issueK = [&](int j) {
#pragma unroll
      for (int k = 0; k < 4; ++k) {
        const int d = wid * 4 + k;
        gll16(ktb + (size_t)d * SK + j * ST + lane * 4, kv + d * ST);
      }
    };
    auto issueV = [&](int j) {
#pragma unroll
      for (int k = 0; k < 4; ++k) {
        const int c = wid * 4 + k;   // chunk = 4 consecutive V rows
        gll16(vb + (size_t)j * (ST * DDIM) + c * 256 + lane * 4, kv + c * 256);
      }
    };

    // ---- stage K tile 0 + Q (async; drained by the barrier) ----
    issueK(0);
    if (wid < 2)
      gll16(qs + ((size_t)nh * LQ + l0) * DDIM + wid * 256 + lane * 4,
            q_lds + wid * 256);
    __syncthreads();   // prev head fully done with kv/part; K0+q visible

    // ---- A1: logits -> p_lds + row max. kv = K tile [d][s] ----
    float rmax0 = NEG_BIG, rmax1 = NEG_BIG;
    const float* qrow0 = q_lds + rr * DDIM;
    const float* qrow1 = q_lds + (rr + 4) * DDIM;

#pragma unroll
    for (int j = 0; j < NT; ++j) {
      const int s = j * ST + cc;
      const float am0 = amask[(size_t)(l0 + rr) * SK + s];      // early issue
      const float am1 = amask[(size_t)(l0 + rr + 4) * SK + s];
      const bool kill = (kpm[n * SK + s] != 0);
      float a0 = 0.f, b0 = 0.f, a1 = 0.f, b1 = 0.f;
#pragma unroll
      for (int d4 = 0; d4 < DDIM; d4 += 4) {
        const float4 q0 = *(const float4*)&qrow0[d4];
        const float4 q1 = *(const float4*)&qrow1[d4];
        const float k0 = kv[(d4 + 0) * ST + cc];
        const float k1 = kv[(d4 + 1) * ST + cc];
        const float k2 = kv[(d4 + 2) * ST + cc];
        const float k3 = kv[(d4 + 3) * ST + cc];
        a0 = fmaf(q0.x, k0, a0); b0 = fmaf(q0.y, k1, b0);
        a0 = fmaf(q0.z, k2, a0); b0 = fmaf(q0.w, k3, b0);
        a1 = fmaf(q1.x, k0, a1); b1 = fmaf(q1.y, k1, b1);
        a1 = fmaf(q1.z, k2, a1); b1 = fmaf(q1.w, k3, b1);
      }
      float l0v = (a0 + b0) * 0.125f + am0;
      float l1v = (a1 + b1) * 0.125f + am1;
      if (kill) { l0v = NEG_BIG; l1v = NEG_BIG; }
      p_lds[(size_t)rr * SK + s]       = l0v;   // logits to LDS, not regs
      p_lds[(size_t)(rr + 4) * SK + s] = l1v;
      rmax0 = fmaxf(rmax0, l0v); rmax1 = fmaxf(rmax1, l1v);
      __syncthreads();  // all reads of kv tile j done
      if (j < NT - 1) {
        issueK(j + 1);
        __syncthreads();  // drain: tile j+1 visible
      }
    }

    // V tile 0 can stage now (kv free); latency hides under the reductions.
    issueV(0);

    // row max: wave w covers rows (w>>2) and (w>>2)+4
    rmax0 = wave_max_f(rmax0); rmax1 = wave_max_f(rmax1);
    if (lane == 0) { red[wid * 2] = rmax0; red[wid * 2 + 1] = rmax1; }
    __syncthreads();      // also drains V0
    if (t < RB) {
      const int g = t & 3, ix = t >> 2;
      float m = red[(4 * g) * 2 + ix];
#pragma unroll
      for (int w = 1; w < 4; ++w) m = fmaxf(m, red[(4 * g + w) * 2 + ix]);
      m_l[t] = m;
    }
    __syncthreads();

    // ---- A2: p = exp(logit - m) in p_lds; row sums -> rinv ----
    const float mm0 = m_l[rr], mm1 = m_l[rr + 4];
    float sum0 = 0.f, sum1 = 0.f;
#pragma unroll
    for (int j = 0; j < NT; ++j) {
      const int s = j * ST + cc;
      const float p0 = __expf(p_lds[(size_t)rr * SK + s] - mm0);
      const float p1 = __expf(p_lds[(size_t)(rr + 4) * SK + s] - mm1);
      p_lds[(size_t)rr * SK + s]       = p0;
      p_lds[(size_t)(rr + 4) * SK + s] = p1;
      sum0 += p0; sum1 += p1;
    }
    sum0 = wave_sum_f(sum0); sum1 = wave_sum_f(sum1);
    if (lane == 0) { red[wid * 2] = sum0; red[wid * 2 + 1] = sum1; }
    __syncthreads();
    if (t < RB) {
      const int g = t & 3, ix = t >> 2;
      float ssum = 0.f;
#pragma unroll
      for (int w = 0; w < 4; ++w) ssum += red[(4 * g + w) * 2 + ix];
      ri_l[t] = 1.0f / ssum;
    }
    __syncthreads();

    // ---- att accumulation (reads own p slots back from LDS) ----
    const float ri0 = ri_l[rr], ri1 = ri_l[rr + 4];
#pragma unroll
    for (int j = 0; j < NT; ++j) {
      const int s = j * ST + cc;
      attA[j] = fmaf(p_lds[(size_t)rr * SK + s],       ri0, attA[j]);
      attB[j] = fmaf(p_lds[(size_t)(rr + 4) * SK + s], ri1, attB[j]);
    }

    // ---- B2: PV. kv = V tile [s][d] (tile 0 already staged+drained) ----
    float ca00 = 0.f, ca01 = 0.f, ca10 = 0.f, ca11 = 0.f;
#pragma unroll
    for (int j = 0; j < NT; ++j) {
      const int sb = sq * 64;
      const float* p0r = p_lds + (size_t)rr * SK + j * ST + sb;
      const float* p1r = p_lds + (size_t)(rr + 4) * SK + j * ST + sb;
#pragma unroll
      for (int s2 = 0; s2 < 64; s2 += 4) {
        const float4 p0 = *(const float4*)&p0r[s2];   // wave-uniform broadcast
        const float4 p1 = *(const float4*)&p1r[s2];
        const float v0 = kv[(sb + s2 + 0) * DDIM + dd];
        const float v1 = kv[(sb + s2 + 1) * DDIM + dd];
        const float v2 = kv[(sb + s2 + 2) * DDIM + dd];
        const float v3 = kv[(sb + s2 + 3) * DDIM + dd];
        ca00 = fmaf(p0.x, v0, ca00); ca01 = fmaf(p0.y, v1, ca01);
        ca00 = fmaf(p0.z, v2, ca00); ca01 = fmaf(p0.w, v3, ca01);
        ca10 = fmaf(p1.x, v0, ca10); ca11 = fmaf(p1.y, v1, ca11);
        ca10 = fmaf(p1.z, v2, ca10); ca11 = fmaf(p1.w, v3, ca11);
      }
      __syncthreads();  // all reads of V tile j done
      if (j < NT - 1) {
        issueV(j + 1);
        __syncthreads();  // drain: tile j+1 visible
      }
    }
    part[(sq * RB + rr) * DDIM + dd]     = ca00 + ca01;
    part[(sq * RB + rr + 4) * DDIM + dd] = ca10 + ca11;
    __syncthreads();
    if (t < RB * DDIM) {  // 512 threads write ctx
      const int r = t >> 6, d = t & 63;
      float sv = 0.f;
#pragma unroll
      for (int q2 = 0; q2 < 4; ++q2) sv += part[(q2 * RB + r) * DDIM + d];
      ctx[((size_t)(l0 + r) * NBATCH + n) * EDIM + h * DDIM + d] = sv * ri_l[r];
    }
    // next head's first barrier protects part/kv reuse
  }

  // ---- final att write (one pass) ----
  const float c16 = 1.0f / (float)HNUM;
#pragma unroll
  for (int j = 0; j < NT; ++j) {
    att[((size_t)n * LQ + l0 + rr) * SK + j * ST + cc]     = attA[j] * c16;
    att[((size_t)n * LQ + l0 + rr + 4) * SK + j * ST + cc] = attB[j] * c16;
  }
}

// ---------------------------------------------------------------------------
extern "C" void kernel_launch(void* const* d_in, const int* in_sizes, int n_in,
                              void* d_out, int out_size, void* d_ws, size_t ws_size,
                              hipStream_t stream)
{
  const float*         query = (const float*)d_in[0];
  const float*         key   = (const float*)d_in[1];
  const float*         value = (const float*)d_in[2];
  const unsigned char* kpm   = (const unsigned char*)d_in[3];
  const float*         amask = (const float*)d_in[4];
  const float*         ipw   = (const float*)d_in[5];
  const float*         ipb   = (const float*)d_in[6];
  const float*         outw  = (const float*)d_in[7];
  const float*         outb  = (const float*)d_in[8];

  float* outp = (float*)d_out;                          // context (L,N,E)
  float* att  = outp + (size_t)LQ * NBATCH * EDIM;      // att (N,L,S)

  // workspace: q_s 16MB | kt_s 16MB | v_s 16MB | ctx 16MB
  const size_t nQ = (size_t)NBATCH * HNUM * LQ * DDIM;
  const size_t needed = (3 * nQ + (size_t)LQ * NBATCH * EDIM) * 4;
  if (ws_size < needed) return;

  float* ws   = (float*)d_ws;
  float* q_s  = ws;
  float* kt_s = q_s  + nQ;
  float* v_s  = kt_s + nQ;
  float* ctx  = v_s  + nQ;

  const int M = LQ * NBATCH;
  dim3 gg(EDIM / 128, M / 128);

  const int lds_bytes = (RB * SK + 16384 + 512 + 2048 + 32 + 8 + 8) * 4;  // 141504
  (void)hipFuncSetAttribute((const void*)attn_k,
                            hipFuncAttributeMaxDynamicSharedMemorySize, lds_bytes);

  gemm_k<1><<<gg, 256, 0, stream>>>(query, ipw,                   ipb,            q_s,  M, EDIM, EDIM, LQ);
  gemm_k<2><<<gg, 256, 0, stream>>>(key,   ipw + EDIM * EDIM,     ipb + EDIM,     kt_s, M, EDIM, EDIM, SK);
  gemm_k<1><<<gg, 256, 0, stream>>>(value, ipw + 2 * EDIM * EDIM, ipb + 2 * EDIM, v_s,  M, EDIM, EDIM, SK);
  attn_k<<<NBATCH * (LQ / RB), 1024, lds_bytes, stream>>>(q_s, kt_s, v_s, amask, kpm, ctx, att);
  gemm_k<0><<<gg, 256, 0, stream>>>(ctx, outw, outb, outp, M, EDIM, EDIM, LQ);
}